// Round 1
// baseline (359.475 us; speedup 1.0000x reference)
//
#include <hip/hip_runtime.h>
#include <hip/hip_bf16.h>

// Fused Damping kernel: B=32768, N=64, H=256, OFF=2016.
// One WG = 32 batch rows. All GEMMs via mfma_f32_16x16x32_bf16 (fp32 accum).
// off tile [32][2016] kept in LDS (bf16) -> never hits HBM.
// Weights pre-packed per launch into MFMA B-fragment layout in d_ws (bf16).

#define BT 32
#define THREADS 512

typedef short short8 __attribute__((ext_vector_type(8)));
typedef float floatx4 __attribute__((ext_vector_type(4)));

__device__ __forceinline__ ushort f2bf(float f) {
    uint u = __builtin_bit_cast(uint, f);
    u += 0x7FFFu + ((u >> 16) & 1u);   // round-to-nearest-even
    return (ushort)(u >> 16);
}
__device__ __forceinline__ float bf2f(ushort h) {
    return __builtin_bit_cast(float, ((uint)h) << 16);
}

// Pack W [K][Ncols] fp32 -> fragment layout [nt][kt][lane][8] bf16.
// Fragment: lane holds B[k = kt*32 + (lane>>4)*8 + j][n = nt*16 + (lane&15)], j=0..7.
// Cols >= Ncols zero-filled (Woo padded 2016 -> 2048).
__global__ void pack_frag(const float* __restrict__ W, ushort* __restrict__ dst,
                          int Ncols, int NT, int KT) {
    int gid = blockIdx.x * blockDim.x + threadIdx.x;
    int total = NT * KT * 64;
    if (gid >= total) return;
    int lane = gid & 63;
    int kt = (gid >> 6) % KT;
    int nt = gid / (64 * KT);
    int q = lane >> 4, ni = lane & 15;
    int col = nt * 16 + ni;
#pragma unroll
    for (int j = 0; j < 8; j++) {
        int k = kt * 32 + q * 8 + j;
        float val = (col < Ncols) ? W[(size_t)k * Ncols + col] : 0.f;
        dst[(size_t)gid * 8 + j] = f2bf(val);
    }
}

// ---- LDS layout (bytes). Total 163,584 <= 160 KiB. ----
// off:  [32][2020] ushort @ 0            (129,280 B)  stride padded for bank spread
// xbf:  [32][88]  ushort @ 0 (overlay in off region; dead before off written)
// act:  [32][264] ushort @ 129280        (16,896 B)   / v: [32][68] f32 overlay after Woo
// xs:   [32][68]  f32    @ 146176        (8,704 B)
// diag: [32][68]  f32    @ 154880        (8,704 B)
#define OSTR 2020
#define ASTR 264
#define DSTR 68
#define XBF_STR 88
#define ACT_BASE 129280
#define XS_BASE 146176
#define DIAG_BASE 154880
#define LDS_BYTES 163584

__global__ __launch_bounds__(THREADS)
void damping_fused(const float* __restrict__ x,
                   const ushort* __restrict__ wd1f, const ushort* __restrict__ wd2f,
                   const ushort* __restrict__ wdof, const ushort* __restrict__ wo1f,
                   const ushort* __restrict__ wo2f, const ushort* __restrict__ woof,
                   const float* __restrict__ bd1, const float* __restrict__ bd2,
                   const float* __restrict__ bdo, const float* __restrict__ bo1,
                   const float* __restrict__ bo2, const float* __restrict__ boo,
                   const float* __restrict__ dmin, float* __restrict__ out) {
    extern __shared__ char smem[];
    ushort* off_s = (ushort*)smem;
    ushort* xbf   = (ushort*)smem;                 // overlay: dead before off written
    ushort* act   = (ushort*)(smem + ACT_BASE);
    float*  v_s   = (float*)(smem + ACT_BASE);     // overlay: live after Woo reads done
    float*  xs    = (float*)(smem + XS_BASE);
    float*  dg    = (float*)(smem + DIAG_BASE);

    const int tid  = threadIdx.x;
    const int lane = tid & 63;
    const int w    = tid >> 6;      // wave 0..7
    const int q    = lane >> 4;
    const int ni   = lane & 15;
    const int b0   = blockIdx.x * BT;

    // ---- load x tile [32][64] fp32 (coalesced float4) ----
    {
        int row = tid >> 4;
        int c = (tid & 15) * 4;
        const float4 xv = *(const float4*)(x + (size_t)(b0 + row) * 64 + c);
        float* xr = xs + row * DSTR + c;
        xr[0] = xv.x; xr[1] = xv.y; xr[2] = xv.z; xr[3] = xv.w;
        ushort* xb = xbf + row * XBF_STR + c;
        xb[0] = f2bf(xv.x); xb[1] = f2bf(xv.y); xb[2] = f2bf(xv.z); xb[3] = f2bf(xv.w);
    }
    __syncthreads();

    const int mt  = w >> 2;         // M-tile 0..1 for MLP layers
    const int ntb = (w & 3) * 4;    // base N-tile for 256-col layers

    // 256-col MLP layer: C[32x256] = A[32xK] @ W, tanh, write into act.
    auto mlp256 = [&](const ushort* Abase, int astr, int KT, const ushort* frag,
                      const float* bias, bool inplace) {
        floatx4 acc[4] = {};
        for (int kt = 0; kt < KT; kt++) {
            const short8 a = *(const short8*)(Abase + (mt * 16 + ni) * astr + kt * 32 + q * 8);
#pragma unroll
            for (int t = 0; t < 4; t++) {
                const short8 bf = *(const short8*)(frag + (size_t)(((ntb + t) * KT + kt) * 64 + lane) * 8);
                acc[t] = __builtin_amdgcn_mfma_f32_16x16x32_bf16(a, bf, acc[t], 0, 0, 0);
            }
        }
        if (inplace) __syncthreads();   // in-place layer: all reads of act done first
#pragma unroll
        for (int t = 0; t < 4; t++) {
            int col = (ntb + t) * 16 + ni;
            float bb = bias[col];
#pragma unroll
            for (int r = 0; r < 4; r++) {
                int row = mt * 16 + q * 4 + r;   // C layout: col=lane&15, row=quad*4+reg
                act[row * ASTR + col] = f2bf(tanhf(acc[t][r] + bb));
            }
        }
        __syncthreads();
    };

    // ---- diag branch ----
    mlp256(xbf, XBF_STR, 2, wd1f, bd1, false);
    mlp256(act, ASTR, 8, wd2f, bd2, true);
    {   // layer3: d[32x64], diag = (relu(d)+dmin)*x
        const int nt3 = w & 3;
        floatx4 acc = {};
        for (int kt = 0; kt < 8; kt++) {
            const short8 a  = *(const short8*)(act + (mt * 16 + ni) * ASTR + kt * 32 + q * 8);
            const short8 bf = *(const short8*)(wdof + (size_t)((nt3 * 8 + kt) * 64 + lane) * 8);
            acc = __builtin_amdgcn_mfma_f32_16x16x32_bf16(a, bf, acc, 0, 0, 0);
        }
        int col = nt3 * 16 + ni;
        float bb = bdo[col], dm = dmin[col];
#pragma unroll
        for (int r = 0; r < 4; r++) {
            int row = mt * 16 + q * 4 + r;
            float d = acc[r] + bb;
            d = (d > 0.f ? d : 0.f) + dm;
            dg[row * DSTR + col] = d * xs[row * DSTR + col];
        }
    }
    __syncthreads();

    // ---- off branch ----
    mlp256(xbf, XBF_STR, 2, wo1f, bo1, false);
    mlp256(act, ASTR, 8, wo2f, bo2, true);

    // ---- Woo GEMM: off[32][2016] = g2 @ Woo + boo, stored bf16 in LDS ----
    {
        floatx4 oacc[16][2] = {};
        for (int kt = 0; kt < 8; kt++) {
            const short8 a0 = *(const short8*)(act + (ni)      * ASTR + kt * 32 + q * 8);
            const short8 a1 = *(const short8*)(act + (16 + ni) * ASTR + kt * 32 + q * 8);
#pragma unroll
            for (int t = 0; t < 16; t++) {
                const int nt = w * 16 + t;
                const short8 bf = *(const short8*)(woof + (size_t)((nt * 8 + kt) * 64 + lane) * 8);
                oacc[t][0] = __builtin_amdgcn_mfma_f32_16x16x32_bf16(a0, bf, oacc[t][0], 0, 0, 0);
                oacc[t][1] = __builtin_amdgcn_mfma_f32_16x16x32_bf16(a1, bf, oacc[t][1], 0, 0, 0);
            }
        }
#pragma unroll
        for (int t = 0; t < 16; t++) {
            const int nt = w * 16 + t;
            if (nt < 126) {             // cols 2016..2047 are pad
                int col = nt * 16 + ni;
                float ob = boo[col];
#pragma unroll
                for (int m = 0; m < 2; m++)
#pragma unroll
                    for (int r = 0; r < 4; r++) {
                        int row = m * 16 + q * 4 + r;
                        off_s[row * OSTR + col] = f2bf(oacc[t][m][r] + ob);
                    }
            }
        }
    }
    __syncthreads();

    // ---- V phase: v_j = diag_j*x_j + sum_{k>j} off[k(k-1)/2+j]*x_k ----
    for (int p = 0; p < 4; p++) {
        int b = p * 8 + w;
        int j = lane;
        float a = dg[b * DSTR + j] * xs[b * DSTR + j];
        for (int k = 1; k < 64; k++) {
            float xk = xs[b * DSTR + k];             // wave-broadcast
            if (j < k) a += bf2f(off_s[b * OSTR + (k * (k - 1)) / 2 + j]) * xk;
        }
        v_s[b * DSTR + j] = a;
    }
    __syncthreads();

    // ---- OUT phase: out_i = diag_i*v_i + sum_{j<i} off[i(i-1)/2+j]*v_j ----
    for (int p = 0; p < 4; p++) {
        int b = p * 8 + w;
        int i = lane;
        float a = dg[b * DSTR + i] * v_s[b * DSTR + i];
        int base = b * OSTR + (i * (i - 1)) / 2;
        for (int j = 0; j < 63; j++) {
            float vj = v_s[b * DSTR + j];            // wave-broadcast
            if (j < i) a += bf2f(off_s[base + j]) * vj;
        }
        out[(size_t)(b0 + b) * 64 + i] = a;
    }
}

extern "C" void kernel_launch(void* const* d_in, const int* in_sizes, int n_in,
                              void* d_out, int out_size, void* d_ws, size_t ws_size,
                              hipStream_t stream) {
    const float* x    = (const float*)d_in[0];
    const float* Wd1  = (const float*)d_in[1];
    const float* bd1  = (const float*)d_in[2];
    const float* Wd2  = (const float*)d_in[3];
    const float* bd2  = (const float*)d_in[4];
    const float* Wdo  = (const float*)d_in[5];
    const float* bdo  = (const float*)d_in[6];
    const float* Wo1  = (const float*)d_in[7];
    const float* bo1  = (const float*)d_in[8];
    const float* Wo2  = (const float*)d_in[9];
    const float* bo2  = (const float*)d_in[10];
    const float* Woo  = (const float*)d_in[11];
    const float* boo  = (const float*)d_in[12];
    const float* dmin = (const float*)d_in[13];
    float* out = (float*)d_out;

    // ws layout (ushort elems): wd1f 16384 | wd2f 65536 | wdof 16384 | wo1f 16384
    //                           | wo2f 65536 | woof 524288  => 1,409,024 bytes
    ushort* ws   = (ushort*)d_ws;
    ushort* wd1f = ws;
    ushort* wd2f = wd1f + 16384;
    ushort* wdof = wd2f + 65536;
    ushort* wo1f = wdof + 16384;
    ushort* wo2f = wo1f + 16384;
    ushort* woof = wo2f + 65536;

    auto packs = [&](const float* W, ushort* dst, int Ncols, int NT, int KT) {
        int total = NT * KT * 64;
        pack_frag<<<(total + 255) / 256, 256, 0, stream>>>(W, dst, Ncols, NT, KT);
    };
    packs(Wd1, wd1f, 256, 16, 2);
    packs(Wd2, wd2f, 256, 16, 8);
    packs(Wdo, wdof, 64, 4, 8);
    packs(Wo1, wo1f, 256, 16, 2);
    packs(Wo2, wo2f, 256, 16, 8);
    packs(Woo, woof, 2016, 128, 8);   // padded to 128 N-tiles (zeros)

    // >64 KB dynamic LDS opt-in (idempotent; host-side, graph-capture safe)
    hipFuncSetAttribute((const void*)damping_fused,
                        hipFuncAttributeMaxDynamicSharedMemorySize, LDS_BYTES);

    damping_fused<<<32768 / BT, THREADS, LDS_BYTES, stream>>>(
        x, wd1f, wd2f, wdof, wo1f, wo2f, woof,
        bd1, bd2, bdo, bo1, bo2, boo, dmin, out);
}